// Round 4
// baseline (679.252 us; speedup 1.0000x reference)
//
#include <hip/hip_runtime.h>

#define N_NODES 100000
#define N_EDGES 3200000
#define DIM 256

#define BROWS 256                 // rows per bucket
#define NBUCK 391                 // ceil(N_NODES / BROWS)

typedef short short8 __attribute__((ext_vector_type(8)));
typedef float f32x4 __attribute__((ext_vector_type(4)));

static __device__ __forceinline__ unsigned short f2bf(float f) {
    unsigned int u = __float_as_uint(f);
    u = (u + 0x7FFFu + ((u >> 16) & 1u)) >> 16;   // RNE
    return (unsigned short)u;
}

// ---------------- CSR build ----------------
__global__ void k_hist(const int* __restrict__ row, int* __restrict__ cnt) {
    int e = blockIdx.x * 256 + threadIdx.x;
    atomicAdd(&cnt[row[e]], 1);
}

__global__ void k_scan1(const int* __restrict__ cnt, int* __restrict__ rs,
                        int* __restrict__ bsum) {
    __shared__ int lds[1024];
    int t = threadIdx.x;
    int g = blockIdx.x * 1024 + t;
    int x = cnt[g];
    lds[t] = x;
    __syncthreads();
    for (int off = 1; off < 1024; off <<= 1) {
        int v = (t >= off) ? lds[t - off] : 0;
        __syncthreads();
        lds[t] += v;
        __syncthreads();
    }
    rs[g] = lds[t] - x;                 // exclusive
    if (t == 1023) bsum[blockIdx.x] = lds[t];
}

__global__ void k_scan2(int* __restrict__ bsum) {   // 1 block, 128 thr, 98 valid
    __shared__ int lds[128];
    int t = threadIdx.x;
    int x = (t < 98) ? bsum[t] : 0;
    lds[t] = x;
    __syncthreads();
    for (int off = 1; off < 128; off <<= 1) {
        int v = (t >= off) ? lds[t - off] : 0;
        __syncthreads();
        lds[t] += v;
        __syncthreads();
    }
    if (t < 98) bsum[t] = lds[t] - x;   // exclusive
}

// final row offsets; also emits bucket cursors (bcur[b] = rs[b*256]).
__global__ void k_scanadd(int* __restrict__ rs, const int* __restrict__ bsum,
                          int* __restrict__ bcur) {
    int g = blockIdx.x * 1024 + threadIdx.x;
    int v = rs[g] + bsum[blockIdx.x];
    rs[g] = v;
    if ((g & 255) == 0 && (g >> 8) < NBUCK) bcur[g >> 8] = v;
}

// Pass 1: block-local counting scatter into per-(block,bucket) contiguous
// sub-segments of tmp. All writers of a cache line are in one block => line is
// assembled inside a single XCD's L2 => ~1 writeback per line.
__global__ __launch_bounds__(512) void k_bucket(const int* __restrict__ row,
                                                const int* __restrict__ col,
                                                const float* __restrict__ val,
                                                int* __restrict__ bcur,
                                                int2* __restrict__ tmp) {
    __shared__ int hist[NBUCK];
    __shared__ int base[NBUCK];
    int t = threadIdx.x;
    const int per = (N_EDGES + gridDim.x - 1) / gridDim.x;   // 12500 @ grid=256
    int e0 = blockIdx.x * per;
    int e1 = min(e0 + per, N_EDGES);
    for (int i = t; i < NBUCK; i += 512) hist[i] = 0;
    __syncthreads();
    for (int e = e0 + t; e < e1; e += 512)
        atomicAdd(&hist[row[e] >> 8], 1);
    __syncthreads();
    for (int i = t; i < NBUCK; i += 512) {
        int c = hist[i];
        base[i] = c ? atomicAdd(&bcur[i], c) : 0;
        hist[i] = 0;                     // reuse as local cursor
    }
    __syncthreads();
    for (int e = e0 + t; e < e1; e += 512) {
        int r = row[e];
        int b = r >> 8;                  // bucket (BROWS = 256)
        int off = atomicAdd(&hist[b], 1);
        // pack: col in bits [0,17), local row in bits [17,25)
        tmp[base[b] + off] = make_int2(((r & 255) << 17) | col[e],
                                       __float_as_int(val[e]));
    }
}

// Pass 2: one block per bucket; place edges at final CSR positions via LDS
// per-row cursors. Random writes confined to this bucket's ~64 KB window.
__global__ __launch_bounds__(256) void k_place(const int* __restrict__ rs,
                                               const int2* __restrict__ tmp,
                                               int2* __restrict__ csr) {
    __shared__ int lcur[BROWS];
    int t = threadIdx.x;
    int rowbase = blockIdx.x * BROWS;
    int rr = rowbase + t;
    lcur[t] = (rr < N_NODES) ? rs[rr] : 0;
    __syncthreads();
    int s = rs[rowbase];
    int e = rs[min(rowbase + BROWS, N_NODES)];
    for (int i = s + t; i < e; i += 256) {
        int2 x = tmp[i];
        int pos = atomicAdd(&lcur[x.x >> 17], 1);
        csr[pos] = make_int2(x.x & 0x1FFFF, x.y);
    }
}

// ---------------- W pack (fp32 -> bf16 fragment layout) ----------------
__global__ void k_wpack(const float* __restrict__ W, unsigned short* __restrict__ wp) {
    int t = blockIdx.x * 256 + threadIdx.x;     // 0..8191
    int lane = t & 63;
    int nt = (t >> 6) & 15;
    int kc = t >> 10;
    int n = nt * 16 + (lane & 15);
    int kbase = kc * 32 + ((lane >> 4) << 3);
    unsigned short* dst = wp + (size_t)t * 8;
#pragma unroll
    for (int j = 0; j < 8; j++) dst[j] = f2bf(W[(size_t)(kbase + j) * DIM + n]);
}

// ---------------- GEMM: sup(bf16) = X @ W, computed as (X@W)^T tiles ----------------
#define LDSTRIDE 528                       // 512 + 16 pad (bank spread), 8B-aligned
__global__ __launch_bounds__(1024, 4) void k_gemm(const float* __restrict__ X,
                                                  const unsigned short* __restrict__ wp,
                                                  unsigned short* __restrict__ sup) {
    __shared__ char pool[16 * 16 * LDSTRIDE];   // 135168 B; W uses first 131072 B
    unsigned short* wlds = (unsigned short*)pool;
    int t = threadIdx.x;
    int wave = t >> 6, lane = t & 63;
    int q = lane >> 4, nl = lane & 15;

    const int nstrips = (N_NODES + 255) / 256;  // 391
    for (int s = blockIdx.x; s < nstrips; s += gridDim.x) {
        for (int i = t; i < 8192; i += 1024)
            ((uint4*)wlds)[i] = ((const uint4*)wp)[i];
        __syncthreads();

        int rowbase = s * 256 + wave * 16;
        f32x4 acc[16];
#pragma unroll
        for (int mt = 0; mt < 16; mt++) acc[mt] = (f32x4){0.f, 0.f, 0.f, 0.f};

        for (int kc = 0; kc < 8; kc++) {
            int r = rowbase + nl;
            short8 b = (short8)0;
            if (r < N_NODES) {
                const float* bp = X + (size_t)r * DIM + kc * 32 + (q << 3);
                float4 b0 = *(const float4*)bp;
                float4 b1 = *(const float4*)(bp + 4);
                b[0] = (short)f2bf(b0.x); b[1] = (short)f2bf(b0.y);
                b[2] = (short)f2bf(b0.z); b[3] = (short)f2bf(b0.w);
                b[4] = (short)f2bf(b1.x); b[5] = (short)f2bf(b1.y);
                b[6] = (short)f2bf(b1.z); b[7] = (short)f2bf(b1.w);
            }
#pragma unroll
            for (int mt = 0; mt < 16; mt++) {
                short8 a = *(const short8*)&wlds[(size_t)(((kc * 16 + mt) * 64) + lane) * 8];
                acc[mt] = __builtin_amdgcn_mfma_f32_16x16x32_bf16(a, b, acc[mt], 0, 0, 0);
            }
        }
        __syncthreads();

        char* wbase = pool + wave * (16 * LDSTRIDE);
#pragma unroll
        for (int mt = 0; mt < 16; mt++) {
            uint2 p;
            p.x = ((unsigned int)f2bf(acc[mt][1]) << 16) | f2bf(acc[mt][0]);
            p.y = ((unsigned int)f2bf(acc[mt][3]) << 16) | f2bf(acc[mt][2]);
            *(uint2*)(wbase + nl * LDSTRIDE + mt * 32 + q * 8) = p;
        }
#pragma unroll
        for (int i = 0; i < 8; i++) {
            int row = 2 * i + (lane >> 5);
            uint4 v = *(const uint4*)(wbase + row * LDSTRIDE + (lane & 31) * 16);
            int node = rowbase + row;
            if (node < N_NODES)
                *(uint4*)((char*)sup + (size_t)node * 512 + (lane & 31) * 16) = v;
        }
        __syncthreads();
    }
}

// ---------------- CSR aggregation (v3: wide groups + 2x unroll, NO shfl broadcast) ----
// One wave per row. 8 lane-groups of 8 handle 8 edges concurrently; each lane
// covers 32 dims (4x dwordx4 gather, 64B). All 8 lanes of a group load the SAME
// csr entry (hardware broadcast) — v1's proven pattern, just wider. Main loop
// processes 16 edges/iter with all 8 gather dwordx4 issued before any FMA =>
// ~8 outstanding 16B loads per lane (4x the MLP of the 672us version).
static __device__ __forceinline__ void fma16(float* acc, float v,
                                             uint4 a0, uint4 a1, uint4 a2, uint4 a3) {
    unsigned int u[16] = {a0.x, a0.y, a0.z, a0.w, a1.x, a1.y, a1.z, a1.w,
                          a2.x, a2.y, a2.z, a2.w, a3.x, a3.y, a3.z, a3.w};
#pragma unroll
    for (int j = 0; j < 16; j++) {
        acc[2 * j]     += v * __uint_as_float(u[j] << 16);
        acc[2 * j + 1] += v * __uint_as_float(u[j] & 0xFFFF0000u);
    }
}

__global__ __launch_bounds__(256) void k_agg(const int* __restrict__ rs,
                                             const int2* __restrict__ csr,
                                             const unsigned short* __restrict__ sup,
                                             const float* __restrict__ bias,
                                             float* __restrict__ out) {
    int wave = threadIdx.x >> 6, lane = threadIdx.x & 63;
    int r = blockIdx.x * 4 + wave;
    int s = rs[r], e = rs[r + 1];
    int g = lane >> 3;          // edge subgroup 0..7
    int L = lane & 7;           // dim slice: dims [L*32, L*32+32)

    float acc[32];
#pragma unroll
    for (int j = 0; j < 32; j++) acc[j] = 0.f;

    int i = s;
    for (; i + 16 <= e; i += 16) {
        int2 ce0 = csr[i + g];
        int2 ce1 = csr[i + 8 + g];
        const uint4* sp0 = (const uint4*)(sup + (size_t)ce0.x * DIM + L * 32);
        const uint4* sp1 = (const uint4*)(sup + (size_t)ce1.x * DIM + L * 32);
        uint4 a0 = sp0[0], a1 = sp0[1], a2 = sp0[2], a3 = sp0[3];
        uint4 b0 = sp1[0], b1 = sp1[1], b2 = sp1[2], b3 = sp1[3];
        fma16(acc, __int_as_float(ce0.y), a0, a1, a2, a3);
        fma16(acc, __int_as_float(ce1.y), b0, b1, b2, b3);
    }
    for (; i + 8 <= e; i += 8) {
        int2 ce = csr[i + g];
        const uint4* sp = (const uint4*)(sup + (size_t)ce.x * DIM + L * 32);
        fma16(acc, __int_as_float(ce.y), sp[0], sp[1], sp[2], sp[3]);
    }
    {   // tail (<8 edges)
        int idx = i + g;
        if (idx < e) {
            int2 ce = csr[idx];
            const uint4* sp = (const uint4*)(sup + (size_t)ce.x * DIM + L * 32);
            fma16(acc, __int_as_float(ce.y), sp[0], sp[1], sp[2], sp[3]);
        }
    }
    // combine groups: lanes {L, L+8, ..., L+56} hold the same dims
#pragma unroll
    for (int j = 0; j < 32; j++) {
        float x = acc[j];
        x += __shfl_down(x, 32, 64);
        x += __shfl_down(x, 16, 64);
        x += __shfl_down(x, 8, 64);
        acc[j] = x;
    }
    if (lane < 8) {
        float4* op = (float4*)(out + (size_t)r * DIM + lane * 32);
        const float4* bp = (const float4*)(bias + lane * 32);
#pragma unroll
        for (int qq = 0; qq < 8; qq++) {
            float4 b = bp[qq];
            float4 o;
            o.x = acc[4 * qq]     + b.x;
            o.y = acc[4 * qq + 1] + b.y;
            o.z = acc[4 * qq + 2] + b.z;
            o.w = acc[4 * qq + 3] + b.w;
            op[qq] = o;
        }
    }
}

extern "C" void kernel_launch(void* const* d_in, const int* in_sizes, int n_in,
                              void* d_out, int out_size, void* d_ws, size_t ws_size,
                              hipStream_t stream) {
    const float* X    = (const float*)d_in[0];
    const int*   erow = (const int*)d_in[1];
    const int*   ecol = (const int*)d_in[2];
    const float* eval = (const float*)d_in[3];
    const float* W    = (const float*)d_in[4];
    const float* bias = (const float*)d_in[5];
    float* out = (float*)d_out;

    // Workspace layout IDENTICAL to the verified baseline (no growth):
    // bcur (391 ints) lives in the unused tail of the bsum region.
    char* ws = (char*)d_ws;
    int*            rsb  = (int*)ws;                          // 102400 ints
    int*            cur  = (int*)(ws + 409600);               // 102400 ints (histogram)
    int*            bsum = (int*)(ws + 819200);               // 98 ints used of 1024
    int*            bcur = (int*)(ws + 819200) + 128;         // 391 ints (bsum tail)
    unsigned short* wp   = (unsigned short*)(ws + 823296);    // 65536 bf16
    int2*           csr  = (int2*)(ws + 954368);              // 3.2M int2 = 25.6 MB
    unsigned short* sup  = (unsigned short*)(ws + 26554368);  // 25.6M bf16 = 51.2 MB
    int2*           tmp  = (int2*)(ws + 26554368);            // aliases sup (dead until k_gemm)

    hipMemsetAsync(cur, 0, 409600, stream);
    k_hist<<<N_EDGES / 256, 256, 0, stream>>>(erow, cur);
    k_scan1<<<98, 1024, 0, stream>>>(cur, rsb, bsum);
    k_scan2<<<1, 128, 0, stream>>>(bsum);
    k_scanadd<<<98, 1024, 0, stream>>>(rsb, bsum, bcur);
    k_bucket<<<256, 512, 0, stream>>>(erow, ecol, eval, bcur, tmp);
    k_place<<<NBUCK, 256, 0, stream>>>(rsb, tmp, csr);
    k_wpack<<<32, 256, 0, stream>>>(W, wp);
    k_gemm<<<256, 1024, 0, stream>>>(X, wp, sup);
    k_agg<<<N_NODES / 4, 256, 0, stream>>>(rsb, csr, sup, bias, out);
}